// Round 4
// baseline (3114.131 us; speedup 1.0000x reference)
//
#include <hip/hip_runtime.h>
#include <math.h>

#define CIN 256
#define HD  64

// ---------------------------------------------------------------------------
// deg[d] += 1 for each edge destination (self-loop +1 folded into k_dinv)
__global__ __launch_bounds__(256) void k_deg(const int* __restrict__ dst,
                                             float* __restrict__ deg, int E) {
  int e = blockIdx.x * 256 + threadIdx.x;
  if (e < E) atomicAdd(&deg[dst[e]], 1.0f);
}

// dinv[i] = rsqrt(deg[i] + 1)   (in-place on deg buffer; deg+1 >= 1 always)
__global__ __launch_bounds__(256) void k_dinv(float* __restrict__ deg, int N) {
  int i = blockIdx.x * 256 + threadIdx.x;
  if (i < N) deg[i] = rsqrtf(deg[i] + 1.0f);
}

// NOTE: parameter must NOT be named `w` — member access `.w` would be
// token-captured by the preprocessor (w.w -> w2.w2).
#define FMA4(ar, xs, wv)            \
  ar[0] = fmaf(xs, wv.x, ar[0]);    \
  ar[1] = fmaf(xs, wv.y, ar[1]);    \
  ar[2] = fmaf(xs, wv.z, ar[2]);    \
  ar[3] = fmaf(xs, wv.w, ar[3]);

// hs[n][j] = dinv[n] * (x[n] @ W1)[j]; acc[n][j] initialized to hs (self-loop)
// block: 256 threads = 64 nodes x 64 j; thread tile 4 nodes x 4 j
__global__ __launch_bounds__(256) void k_gemm1(const float* __restrict__ x,
                                               const float* __restrict__ W1,
                                               const float* __restrict__ dinv,
                                               float* __restrict__ hs,
                                               float* __restrict__ acc, int N) {
  __shared__ float Wl[CIN * HD];  // 64 KiB
  int tid = threadIdx.x;
#pragma unroll
  for (int i = 0; i < (CIN * HD) / 256; ++i) Wl[tid + i * 256] = W1[tid + i * 256];
  __syncthreads();

  int tn = tid >> 4, tj = tid & 15;
  int n0 = blockIdx.x * 64 + tn * 4;
  int j0 = tj * 4;

  const float* xp0 = x + (size_t)(n0 + 0 < N ? n0 + 0 : N - 1) * CIN;
  const float* xp1 = x + (size_t)(n0 + 1 < N ? n0 + 1 : N - 1) * CIN;
  const float* xp2 = x + (size_t)(n0 + 2 < N ? n0 + 2 : N - 1) * CIN;
  const float* xp3 = x + (size_t)(n0 + 3 < N ? n0 + 3 : N - 1) * CIN;

  float a[4][4] = {};
  for (int c = 0; c < CIN; c += 4) {
    float4 w0 = *(const float4*)&Wl[(c + 0) * HD + j0];
    float4 w1 = *(const float4*)&Wl[(c + 1) * HD + j0];
    float4 w2 = *(const float4*)&Wl[(c + 2) * HD + j0];
    float4 w3 = *(const float4*)&Wl[(c + 3) * HD + j0];
    float4 x0 = *(const float4*)(xp0 + c);
    float4 x1 = *(const float4*)(xp1 + c);
    float4 x2 = *(const float4*)(xp2 + c);
    float4 x3 = *(const float4*)(xp3 + c);
    FMA4(a[0], x0.x, w0); FMA4(a[0], x0.y, w1); FMA4(a[0], x0.z, w2); FMA4(a[0], x0.w, w3);
    FMA4(a[1], x1.x, w0); FMA4(a[1], x1.y, w1); FMA4(a[1], x1.z, w2); FMA4(a[1], x1.w, w3);
    FMA4(a[2], x2.x, w0); FMA4(a[2], x2.y, w1); FMA4(a[2], x2.z, w2); FMA4(a[2], x2.w, w3);
    FMA4(a[3], x3.x, w0); FMA4(a[3], x3.y, w1); FMA4(a[3], x3.z, w2); FMA4(a[3], x3.w, w3);
  }

#pragma unroll
  for (int i = 0; i < 4; ++i) {
    int n = n0 + i;
    if (n < N) {
      float dv = dinv[n];
      float4 v = make_float4(a[i][0] * dv, a[i][1] * dv, a[i][2] * dv, a[i][3] * dv);
      *(float4*)&hs[(size_t)n * HD + j0]  = v;
      *(float4*)&acc[(size_t)n * HD + j0] = v;
    }
  }
}

// scatter-add: acc[dst[e]][:] += hs[src[e]][:]   (16 lanes per edge, float4)
__global__ __launch_bounds__(256) void k_scatter(const int* __restrict__ src,
                                                 const int* __restrict__ dst,
                                                 const float* __restrict__ hs,
                                                 float* __restrict__ acc, int E) {
  int t = blockIdx.x * 256 + threadIdx.x;
  int e = t >> 4;
  if (e < E) {
    int q = (t & 15) * 4;
    int s = src[e], d = dst[e];
    float4 v = *(const float4*)&hs[(size_t)s * HD + q];
    float* p = &acc[(size_t)d * HD + q];
    atomicAdd(p + 0, v.x);
    atomicAdd(p + 1, v.y);
    atomicAdd(p + 2, v.z);
    atomicAdd(p + 3, v.w);
  }
}

// h1 = relu(acc*dinv + b1); write hs = h1*dinv (next layer's scaled message)
// and acc = same (self-loop init for layer-2 aggregation). In-place.
__global__ __launch_bounds__(256) void k_fin1(const float* __restrict__ b1,
                                              const float* __restrict__ dinv,
                                              float* __restrict__ acc,
                                              float* __restrict__ hs, int N64) {
  int t = blockIdx.x * 256 + threadIdx.x;
  if (t < N64) {
    int n = t >> 6, j = t & 63;
    float dv = dinv[n];
    float v = fmaf(acc[t], dv, b1[j]);
    v = fmaxf(v, 0.0f);
    v *= dv;
    hs[t] = v;
    acc[t] = v;
  }
}

__device__ inline float fast_tanh(float v) {
  v = fminf(fmaxf(v, -15.0f), 15.0f);
  float e2 = __expf(2.0f * v);
  return (e2 - 1.0f) * __builtin_amdgcn_rcpf(e2 + 1.0f);
}

// out[n][c] = tanh(dinv[n]*acc2[n][:] @ W2[:, c] + b2[c])
// grid.y = 4 column groups of 64; block tile 64 nodes x 64 cols
__global__ __launch_bounds__(256) void k_gemm2(const float* __restrict__ acc2,
                                               const float* __restrict__ W2,
                                               const float* __restrict__ dinv,
                                               const float* __restrict__ b2,
                                               float* __restrict__ out, int N) {
  __shared__ float Wl[HD * 64];  // 16 KiB chunk: [k][jj]
  int tid = threadIdx.x;
  int cb = blockIdx.y * 64;
#pragma unroll
  for (int i = 0; i < (HD * 64) / 256; ++i) {
    int idx = tid + i * 256;
    Wl[idx] = W2[(idx >> 6) * 256 + cb + (idx & 63)];
  }
  __syncthreads();

  int tn = tid >> 4, tj = tid & 15;
  int n0 = blockIdx.x * 64 + tn * 4;
  int j0 = tj * 4;

  const float* hp0 = acc2 + (size_t)(n0 + 0 < N ? n0 + 0 : N - 1) * HD;
  const float* hp1 = acc2 + (size_t)(n0 + 1 < N ? n0 + 1 : N - 1) * HD;
  const float* hp2 = acc2 + (size_t)(n0 + 2 < N ? n0 + 2 : N - 1) * HD;
  const float* hp3 = acc2 + (size_t)(n0 + 3 < N ? n0 + 3 : N - 1) * HD;

  float a[4][4] = {};
  for (int k = 0; k < HD; k += 4) {
    float4 w0 = *(const float4*)&Wl[(k + 0) * 64 + j0];
    float4 w1 = *(const float4*)&Wl[(k + 1) * 64 + j0];
    float4 w2 = *(const float4*)&Wl[(k + 2) * 64 + j0];
    float4 w3 = *(const float4*)&Wl[(k + 3) * 64 + j0];
    float4 x0 = *(const float4*)(hp0 + k);
    float4 x1 = *(const float4*)(hp1 + k);
    float4 x2 = *(const float4*)(hp2 + k);
    float4 x3 = *(const float4*)(hp3 + k);
    FMA4(a[0], x0.x, w0); FMA4(a[0], x0.y, w1); FMA4(a[0], x0.z, w2); FMA4(a[0], x0.w, w3);
    FMA4(a[1], x1.x, w0); FMA4(a[1], x1.y, w1); FMA4(a[1], x1.z, w2); FMA4(a[1], x1.w, w3);
    FMA4(a[2], x2.x, w0); FMA4(a[2], x2.y, w1); FMA4(a[2], x2.z, w2); FMA4(a[2], x2.w, w3);
    FMA4(a[3], x3.x, w0); FMA4(a[3], x3.y, w1); FMA4(a[3], x3.z, w2); FMA4(a[3], x3.w, w3);
  }

#pragma unroll
  for (int i = 0; i < 4; ++i) {
    int n = n0 + i;
    if (n < N) {
      float dv = dinv[n];
      float4 r;
      r.x = fast_tanh(fmaf(a[i][0], dv, b2[cb + j0 + 0]));
      r.y = fast_tanh(fmaf(a[i][1], dv, b2[cb + j0 + 1]));
      r.z = fast_tanh(fmaf(a[i][2], dv, b2[cb + j0 + 2]));
      r.w = fast_tanh(fmaf(a[i][3], dv, b2[cb + j0 + 3]));
      *(float4*)&out[(size_t)n * 256 + cb + j0] = r;
    }
  }
}

extern "C" void kernel_launch(void* const* d_in, const int* in_sizes, int n_in,
                              void* d_out, int out_size, void* d_ws, size_t ws_size,
                              hipStream_t stream) {
  const float* x  = (const float*)d_in[0];
  const int*   ei = (const int*)d_in[1];
  const float* W1 = (const float*)d_in[2];
  const float* b1 = (const float*)d_in[3];
  const float* W2 = (const float*)d_in[4];
  const float* b2 = (const float*)d_in[5];
  float* out = (float*)d_out;

  int N = in_sizes[0] / CIN;   // 100000
  int E = in_sizes[1] / 2;     // 1600000
  const int* src = ei;
  const int* dst = ei + E;

  char* ws = (char*)d_ws;
  float* dinv = (float*)ws;
  size_t dinv_bytes = (((size_t)N * 4) + 255) & ~(size_t)255;
  float* bufA = (float*)(ws + dinv_bytes);       // h_scaled messages  [N*64]
  float* bufB = bufA + (size_t)N * HD;           // accumulators       [N*64]

  hipMemsetAsync(dinv, 0, (size_t)N * 4, stream);
  k_deg<<<(E + 255) / 256, 256, 0, stream>>>(dst, dinv, E);
  k_dinv<<<(N + 255) / 256, 256, 0, stream>>>(dinv, N);
  k_gemm1<<<(N + 63) / 64, 256, 0, stream>>>(x, W1, dinv, bufA, bufB, N);
  k_scatter<<<((size_t)E * 16 + 255) / 256, 256, 0, stream>>>(src, dst, bufA, bufB, E);
  k_fin1<<<((size_t)N * HD + 255) / 256, 256, 0, stream>>>(b1, dinv, bufB, bufA, N * HD);
  k_scatter<<<((size_t)E * 16 + 255) / 256, 256, 0, stream>>>(src, dst, bufA, bufB, E);
  dim3 g2((N + 63) / 64, 4);
  k_gemm2<<<g2, 256, 0, stream>>>(bufB, W2, dinv, b2, out, N);
}

// Round 7
// 607.008 us; speedup vs baseline: 5.1303x; 5.1303x over previous
//
#include <hip/hip_runtime.h>
#include <math.h>

#define CIN 256
#define HD  64

// ===================== CSR build =====================
__global__ __launch_bounds__(256) void k_hist(const int* __restrict__ dst,
                                              int* __restrict__ deg, int E) {
  int e = blockIdx.x * 256 + threadIdx.x;
  if (e < E) atomicAdd(&deg[dst[e]], 1);
}

__global__ __launch_bounds__(256) void k_dinv2(const int* __restrict__ deg,
                                               float* __restrict__ dinv, int N) {
  int i = blockIdx.x * 256 + threadIdx.x;
  if (i < N) dinv[i] = rsqrtf((float)deg[i] + 1.0f);
}

// block-local exclusive scan of deg -> rowstart (local), block sums -> partials
__global__ __launch_bounds__(256) void k_scan1(const int* __restrict__ deg,
                                               int* __restrict__ rowstart,
                                               int* __restrict__ partials, int N) {
  __shared__ int sh[256];
  int g = blockIdx.x * 256 + threadIdx.x;
  int v = (g < N) ? deg[g] : 0;
  sh[threadIdx.x] = v;
  __syncthreads();
  int acc = v;
  for (int off = 1; off < 256; off <<= 1) {
    int t = 0;
    if ((int)threadIdx.x >= off) t = sh[threadIdx.x - off];
    __syncthreads();
    acc += t;
    sh[threadIdx.x] = acc;
    __syncthreads();
  }
  if (g < N) rowstart[g] = acc - v;
  if (threadIdx.x == 255) partials[blockIdx.x] = acc;
}

// exclusive scan of partials (nblk <= 512 fast path; serial fallback)
__global__ __launch_bounds__(512) void k_scan2(int* __restrict__ partials, int nblk) {
  if (nblk > 512) {
    if (threadIdx.x == 0) {
      int run = 0;
      for (int i = 0; i < nblk; ++i) { int t = partials[i]; partials[i] = run; run += t; }
    }
    return;
  }
  __shared__ int sh[512];
  int v = ((int)threadIdx.x < nblk) ? partials[threadIdx.x] : 0;
  sh[threadIdx.x] = v;
  __syncthreads();
  int acc = v;
  for (int off = 1; off < 512; off <<= 1) {
    int t = 0;
    if ((int)threadIdx.x >= off) t = sh[threadIdx.x - off];
    __syncthreads();
    acc += t;
    sh[threadIdx.x] = acc;
    __syncthreads();
  }
  if ((int)threadIdx.x < nblk) partials[threadIdx.x] = acc - v;
}

__global__ __launch_bounds__(256) void k_scan3(int* __restrict__ rowstart,
                                               const int* __restrict__ partials, int N) {
  int g = blockIdx.x * 256 + threadIdx.x;
  if (g < N) rowstart[g] += partials[blockIdx.x];
}

__global__ __launch_bounds__(256) void k_fill(const int* __restrict__ src,
                                              const int* __restrict__ dst,
                                              const int* __restrict__ rowstart,
                                              int* __restrict__ fill,
                                              int* __restrict__ csr, int E) {
  int e = blockIdx.x * 256 + threadIdx.x;
  if (e < E) {
    int d = dst[e];
    int p = atomicAdd(&fill[d], 1);
    csr[rowstart[d] + p] = src[e];
  }
}

// ===================== gather aggregation (no atomics) =====================
// acc[n][:] = hs[n][:] (self) + sum over incoming edges hs[src][:]
// 16 lanes per node, float4 each.
__global__ __launch_bounds__(256) void k_agg(const int* __restrict__ rowstart,
                                             const int* __restrict__ deg,
                                             const int* __restrict__ csr,
                                             const float* __restrict__ hs,
                                             float* __restrict__ acc, int N) {
  int t = blockIdx.x * 256 + threadIdx.x;
  int n = t >> 4;
  if (n >= N) return;
  int qc = t & 15;
  const float4* hp = (const float4*)hs;
  float4 a = hp[(size_t)n * 16 + qc];
  int r0 = rowstart[n], dg = deg[n];
  for (int i = 0; i < dg; ++i) {
    int s = csr[r0 + i];
    float4 v = hp[(size_t)s * 16 + qc];
    a.x += v.x; a.y += v.y; a.z += v.z; a.w += v.w;
  }
  ((float4*)acc)[(size_t)n * 16 + qc] = a;
}

// ===================== dense kernels =====================
// NOTE: macro parameter must NOT be named `w` (preprocessor token capture on .w)
#define FMA4(ar, xs, wv)            \
  ar[0] = fmaf(xs, wv.x, ar[0]);    \
  ar[1] = fmaf(xs, wv.y, ar[1]);    \
  ar[2] = fmaf(xs, wv.z, ar[2]);    \
  ar[3] = fmaf(xs, wv.w, ar[3]);

// hs[n][j] = dinv[n] * (x[n] @ W1)[j]; acc initialized too (used by fallback)
__global__ __launch_bounds__(256) void k_gemm1(const float* __restrict__ x,
                                               const float* __restrict__ W1,
                                               const float* __restrict__ dinv,
                                               float* __restrict__ hs,
                                               float* __restrict__ acc, int N) {
  __shared__ float Wl[CIN * HD];  // 64 KiB
  int tid = threadIdx.x;
#pragma unroll
  for (int i = 0; i < (CIN * HD) / 256; ++i) Wl[tid + i * 256] = W1[tid + i * 256];
  __syncthreads();

  int tn = tid >> 4, tj = tid & 15;
  int n0 = blockIdx.x * 64 + tn * 4;
  int j0 = tj * 4;

  const float* xp0 = x + (size_t)(n0 + 0 < N ? n0 + 0 : N - 1) * CIN;
  const float* xp1 = x + (size_t)(n0 + 1 < N ? n0 + 1 : N - 1) * CIN;
  const float* xp2 = x + (size_t)(n0 + 2 < N ? n0 + 2 : N - 1) * CIN;
  const float* xp3 = x + (size_t)(n0 + 3 < N ? n0 + 3 : N - 1) * CIN;

  float a[4][4] = {};
  for (int c = 0; c < CIN; c += 4) {
    float4 w0 = *(const float4*)&Wl[(c + 0) * HD + j0];
    float4 w1 = *(const float4*)&Wl[(c + 1) * HD + j0];
    float4 w2 = *(const float4*)&Wl[(c + 2) * HD + j0];
    float4 w3 = *(const float4*)&Wl[(c + 3) * HD + j0];
    float4 x0 = *(const float4*)(xp0 + c);
    float4 x1 = *(const float4*)(xp1 + c);
    float4 x2 = *(const float4*)(xp2 + c);
    float4 x3 = *(const float4*)(xp3 + c);
    FMA4(a[0], x0.x, w0); FMA4(a[0], x0.y, w1); FMA4(a[0], x0.z, w2); FMA4(a[0], x0.w, w3);
    FMA4(a[1], x1.x, w0); FMA4(a[1], x1.y, w1); FMA4(a[1], x1.z, w2); FMA4(a[1], x1.w, w3);
    FMA4(a[2], x2.x, w0); FMA4(a[2], x2.y, w1); FMA4(a[2], x2.z, w2); FMA4(a[2], x2.w, w3);
    FMA4(a[3], x3.x, w0); FMA4(a[3], x3.y, w1); FMA4(a[3], x3.z, w2); FMA4(a[3], x3.w, w3);
  }

#pragma unroll
  for (int i = 0; i < 4; ++i) {
    int n = n0 + i;
    if (n < N) {
      float dv = dinv[n];
      float4 v = make_float4(a[i][0] * dv, a[i][1] * dv, a[i][2] * dv, a[i][3] * dv);
      *(float4*)&hs[(size_t)n * HD + j0]  = v;
      *(float4*)&acc[(size_t)n * HD + j0] = v;
    }
  }
}

// fallback scatter-add path (atomics) — used only if ws_size too small for CSR
__global__ __launch_bounds__(256) void k_scatter(const int* __restrict__ src,
                                                 const int* __restrict__ dst,
                                                 const float* __restrict__ hs,
                                                 float* __restrict__ acc, int E) {
  int t = blockIdx.x * 256 + threadIdx.x;
  int e = t >> 4;
  if (e < E) {
    int q = (t & 15) * 4;
    int s = src[e], d = dst[e];
    float4 v = *(const float4*)&hs[(size_t)s * HD + q];
    float* p = &acc[(size_t)d * HD + q];
    atomicAdd(p + 0, v.x);
    atomicAdd(p + 1, v.y);
    atomicAdd(p + 2, v.z);
    atomicAdd(p + 3, v.w);
  }
}

__global__ __launch_bounds__(256) void k_deg(const int* __restrict__ dst,
                                             float* __restrict__ deg, int E) {
  int e = blockIdx.x * 256 + threadIdx.x;
  if (e < E) atomicAdd(&deg[dst[e]], 1.0f);
}
__global__ __launch_bounds__(256) void k_dinv(float* __restrict__ deg, int N) {
  int i = blockIdx.x * 256 + threadIdx.x;
  if (i < N) deg[i] = rsqrtf(deg[i] + 1.0f);
}

// h1 = relu(acc*dinv + b1); hs = h1*dinv; acc = same (fallback self-loop init)
__global__ __launch_bounds__(256) void k_fin1(const float* __restrict__ b1,
                                              const float* __restrict__ dinv,
                                              float* __restrict__ acc,
                                              float* __restrict__ hs, int N64) {
  int t = blockIdx.x * 256 + threadIdx.x;
  if (t < N64) {
    int n = t >> 6, j = t & 63;
    float dv = dinv[n];
    float v = fmaf(acc[t], dv, b1[j]);
    v = fmaxf(v, 0.0f);
    v *= dv;
    hs[t] = v;
    acc[t] = v;
  }
}

__device__ inline float fast_tanh(float v) {
  v = fminf(fmaxf(v, -15.0f), 15.0f);
  float e2 = __expf(2.0f * v);
  return (e2 - 1.0f) * __builtin_amdgcn_rcpf(e2 + 1.0f);
}

// out[n][c] = tanh(dinv[n]*acc2[n][:] @ W2[:, c] + b2[c])
__global__ __launch_bounds__(256) void k_gemm2(const float* __restrict__ acc2,
                                               const float* __restrict__ W2,
                                               const float* __restrict__ dinv,
                                               const float* __restrict__ b2,
                                               float* __restrict__ out, int N) {
  __shared__ float Wl[HD * 64];  // [k][jj] chunk of 64 cols
  int tid = threadIdx.x;
  int cb = blockIdx.y * 64;
#pragma unroll
  for (int i = 0; i < (HD * 64) / 256; ++i) {
    int idx = tid + i * 256;
    Wl[idx] = W2[(idx >> 6) * 256 + cb + (idx & 63)];
  }
  __syncthreads();

  int tn = tid >> 4, tj = tid & 15;
  int n0 = blockIdx.x * 64 + tn * 4;
  int j0 = tj * 4;

  const float* hp0 = acc2 + (size_t)(n0 + 0 < N ? n0 + 0 : N - 1) * HD;
  const float* hp1 = acc2 + (size_t)(n0 + 1 < N ? n0 + 1 : N - 1) * HD;
  const float* hp2 = acc2 + (size_t)(n0 + 2 < N ? n0 + 2 : N - 1) * HD;
  const float* hp3 = acc2 + (size_t)(n0 + 3 < N ? n0 + 3 : N - 1) * HD;

  float a[4][4] = {};
  for (int k = 0; k < HD; k += 4) {
    float4 w0 = *(const float4*)&Wl[(k + 0) * 64 + j0];
    float4 w1 = *(const float4*)&Wl[(k + 1) * 64 + j0];
    float4 w2 = *(const float4*)&Wl[(k + 2) * 64 + j0];
    float4 w3 = *(const float4*)&Wl[(k + 3) * 64 + j0];
    float4 x0 = *(const float4*)(hp0 + k);
    float4 x1 = *(const float4*)(hp1 + k);
    float4 x2 = *(const float4*)(hp2 + k);
    float4 x3 = *(const float4*)(hp3 + k);
    FMA4(a[0], x0.x, w0); FMA4(a[0], x0.y, w1); FMA4(a[0], x0.z, w2); FMA4(a[0], x0.w, w3);
    FMA4(a[1], x1.x, w0); FMA4(a[1], x1.y, w1); FMA4(a[1], x1.z, w2); FMA4(a[1], x1.w, w3);
    FMA4(a[2], x2.x, w0); FMA4(a[2], x2.y, w1); FMA4(a[2], x2.z, w2); FMA4(a[2], x2.w, w3);
    FMA4(a[3], x3.x, w0); FMA4(a[3], x3.y, w1); FMA4(a[3], x3.z, w2); FMA4(a[3], x3.w, w3);
  }

#pragma unroll
  for (int i = 0; i < 4; ++i) {
    int n = n0 + i;
    if (n < N) {
      float dv = dinv[n];
      float4 r;
      r.x = fast_tanh(fmaf(a[i][0], dv, b2[cb + j0 + 0]));
      r.y = fast_tanh(fmaf(a[i][1], dv, b2[cb + j0 + 1]));
      r.z = fast_tanh(fmaf(a[i][2], dv, b2[cb + j0 + 2]));
      r.w = fast_tanh(fmaf(a[i][3], dv, b2[cb + j0 + 3]));
      *(float4*)&out[(size_t)n * 256 + cb + j0] = r;
    }
  }
}

extern "C" void kernel_launch(void* const* d_in, const int* in_sizes, int n_in,
                              void* d_out, int out_size, void* d_ws, size_t ws_size,
                              hipStream_t stream) {
  const float* x  = (const float*)d_in[0];
  const int*   ei = (const int*)d_in[1];
  const float* W1 = (const float*)d_in[2];
  const float* b1 = (const float*)d_in[3];
  const float* W2 = (const float*)d_in[4];
  const float* b2 = (const float*)d_in[5];
  float* out = (float*)d_out;

  int N = in_sizes[0] / CIN;   // 100000
  int E = in_sizes[1] / 2;     // 1600000
  const int* src = ei;
  const int* dst = ei + E;

  auto align256 = [](size_t v) { return (v + 255) & ~(size_t)255; };
  size_t nb  = align256((size_t)N * 4);
  size_t eb  = align256((size_t)E * 4);
  size_t fb  = align256((size_t)N * HD * 4);

  // CSR layout: dinv | deg | rowstart | fill | partials | csr | bufA | bufB
  size_t need = nb * 4 + align256(512 * 4) + eb + fb * 2;

  char* ws = (char*)d_ws;
  int nblk = (N + 255) / 256;

  if (ws_size >= need) {
    float* dinv     = (float*)ws;
    int*   deg      = (int*)(ws + nb);
    int*   rowstart = (int*)(ws + nb * 2);
    int*   fillc    = (int*)(ws + nb * 3);
    int*   partials = (int*)(ws + nb * 4);
    int*   csr      = (int*)(ws + nb * 4 + align256(512 * 4));
    float* bufA     = (float*)(ws + nb * 4 + align256(512 * 4) + eb);
    float* bufB     = bufA + (size_t)N * HD;

    hipMemsetAsync(deg,   0, (size_t)N * 4, stream);
    hipMemsetAsync(fillc, 0, (size_t)N * 4, stream);
    k_hist <<<(E + 255) / 256, 256, 0, stream>>>(dst, deg, E);
    k_dinv2<<<nblk, 256, 0, stream>>>(deg, dinv, N);
    k_scan1<<<nblk, 256, 0, stream>>>(deg, rowstart, partials, N);
    k_scan2<<<1, 512, 0, stream>>>(partials, nblk);
    k_scan3<<<nblk, 256, 0, stream>>>(rowstart, partials, N);
    k_fill <<<(E + 255) / 256, 256, 0, stream>>>(src, dst, rowstart, fillc, csr, E);

    k_gemm1<<<(N + 63) / 64, 256, 0, stream>>>(x, W1, dinv, bufA, bufB, N);
    k_agg  <<<((size_t)N * 16 + 255) / 256, 256, 0, stream>>>(rowstart, deg, csr, bufA, bufB, N);
    k_fin1 <<<((size_t)N * HD + 255) / 256, 256, 0, stream>>>(b1, dinv, bufB, bufA, N * HD);
    k_agg  <<<((size_t)N * 16 + 255) / 256, 256, 0, stream>>>(rowstart, deg, csr, bufA, bufB, N);
    dim3 g2((N + 63) / 64, 4);
    k_gemm2<<<g2, 256, 0, stream>>>(bufB, W2, dinv, b2, out, N);
  } else {
    // fallback: atomic scatter path (verified working)
    float* dinv = (float*)ws;
    float* bufA = (float*)(ws + nb);
    float* bufB = bufA + (size_t)N * HD;

    hipMemsetAsync(dinv, 0, (size_t)N * 4, stream);
    k_deg <<<(E + 255) / 256, 256, 0, stream>>>(dst, dinv, E);
    k_dinv<<<nblk, 256, 0, stream>>>(dinv, N);
    k_gemm1<<<(N + 63) / 64, 256, 0, stream>>>(x, W1, dinv, bufA, bufB, N);
    k_scatter<<<((size_t)E * 16 + 255) / 256, 256, 0, stream>>>(src, dst, bufA, bufB, E);
    k_fin1<<<((size_t)N * HD + 255) / 256, 256, 0, stream>>>(b1, dinv, bufB, bufA, N * HD);
    k_scatter<<<((size_t)E * 16 + 255) / 256, 256, 0, stream>>>(src, dst, bufA, bufB, E);
    dim3 g2((N + 63) / 64, 4);
    k_gemm2<<<g2, 256, 0, stream>>>(bufB, W2, dinv, b2, out, N);
  }
}

// Round 8
// 571.914 us; speedup vs baseline: 5.4451x; 1.0614x over previous
//
#include <hip/hip_runtime.h>
#include <math.h>

#define CIN 256
#define HD  64

// ===================== CSR build =====================
__global__ __launch_bounds__(256) void k_hist(const int* __restrict__ dst,
                                              int* __restrict__ deg, int E) {
  int e = blockIdx.x * 256 + threadIdx.x;
  if (e < E) atomicAdd(&deg[dst[e]], 1);
}

__global__ __launch_bounds__(256) void k_dinv2(const int* __restrict__ deg,
                                               float* __restrict__ dinv, int N) {
  int i = blockIdx.x * 256 + threadIdx.x;
  if (i < N) dinv[i] = rsqrtf((float)deg[i] + 1.0f);
}

// block-local exclusive scan of deg -> rowstart (local), block sums -> partials
__global__ __launch_bounds__(256) void k_scan1(const int* __restrict__ deg,
                                               int* __restrict__ rowstart,
                                               int* __restrict__ partials, int N) {
  __shared__ int sh[256];
  int g = blockIdx.x * 256 + threadIdx.x;
  int v = (g < N) ? deg[g] : 0;
  sh[threadIdx.x] = v;
  __syncthreads();
  int acc = v;
  for (int off = 1; off < 256; off <<= 1) {
    int t = 0;
    if ((int)threadIdx.x >= off) t = sh[threadIdx.x - off];
    __syncthreads();
    acc += t;
    sh[threadIdx.x] = acc;
    __syncthreads();
  }
  if (g < N) rowstart[g] = acc - v;
  if (threadIdx.x == 255) partials[blockIdx.x] = acc;
}

// exclusive scan of partials (nblk <= 512 fast path; serial fallback)
__global__ __launch_bounds__(512) void k_scan2(int* __restrict__ partials, int nblk) {
  if (nblk > 512) {
    if (threadIdx.x == 0) {
      int run = 0;
      for (int i = 0; i < nblk; ++i) { int t = partials[i]; partials[i] = run; run += t; }
    }
    return;
  }
  __shared__ int sh[512];
  int v = ((int)threadIdx.x < nblk) ? partials[threadIdx.x] : 0;
  sh[threadIdx.x] = v;
  __syncthreads();
  int acc = v;
  for (int off = 1; off < 512; off <<= 1) {
    int t = 0;
    if ((int)threadIdx.x >= off) t = sh[threadIdx.x - off];
    __syncthreads();
    acc += t;
    sh[threadIdx.x] = acc;
    __syncthreads();
  }
  if ((int)threadIdx.x < nblk) partials[threadIdx.x] = acc - v;
}

__global__ __launch_bounds__(256) void k_scan3(int* __restrict__ rowstart,
                                               const int* __restrict__ partials, int N) {
  int g = blockIdx.x * 256 + threadIdx.x;
  if (g < N) rowstart[g] += partials[blockIdx.x];
}

__global__ __launch_bounds__(256) void k_fill(const int* __restrict__ src,
                                              const int* __restrict__ dst,
                                              const int* __restrict__ rowstart,
                                              int* __restrict__ fill,
                                              int* __restrict__ csr, int E) {
  int e = blockIdx.x * 256 + threadIdx.x;
  if (e < E) {
    int d = dst[e];
    int p = atomicAdd(&fill[d], 1);
    csr[rowstart[d] + p] = src[e];
  }
}

// ===================== gather aggregation (no atomics) =====================
// out[n][:] = hs[n][:] (self) + sum over incoming edges hs[src][:]
// FUSE: apply h = relu(sum*dinv + b1) * dinv epilogue (layer-1 finalize).
// 16 lanes per node, float4 each. csr-index prefetch for ILP.
template <bool FUSE>
__global__ __launch_bounds__(256) void k_agg(const int* __restrict__ rowstart,
                                             const int* __restrict__ deg,
                                             const int* __restrict__ csr,
                                             const float* __restrict__ hs,
                                             float* __restrict__ outb,
                                             const float* __restrict__ dinv,
                                             const float* __restrict__ b1, int N) {
  int t = blockIdx.x * 256 + threadIdx.x;
  int n = t >> 4;
  if (n >= N) return;
  int qc = t & 15;
  const float4* hp = (const float4*)hs;
  float4 a = hp[(size_t)n * 16 + qc];   // self-loop term
  int r0 = rowstart[n], dg = deg[n];
  if (dg > 0) {
    int s = csr[r0];
    for (int i = 1; i < dg; ++i) {
      int s_next = csr[r0 + i];          // prefetch next index
      float4 v = hp[(size_t)s * 16 + qc];
      a.x += v.x; a.y += v.y; a.z += v.z; a.w += v.w;
      s = s_next;
    }
    float4 v = hp[(size_t)s * 16 + qc];
    a.x += v.x; a.y += v.y; a.z += v.z; a.w += v.w;
  }
  if (FUSE) {
    float dv = dinv[n];
    float4 bb = *(const float4*)&b1[qc * 4];
    a.x = fmaxf(fmaf(a.x, dv, bb.x), 0.0f) * dv;
    a.y = fmaxf(fmaf(a.y, dv, bb.y), 0.0f) * dv;
    a.z = fmaxf(fmaf(a.z, dv, bb.z), 0.0f) * dv;
    a.w = fmaxf(fmaf(a.w, dv, bb.w), 0.0f) * dv;
  }
  ((float4*)outb)[(size_t)n * 16 + qc] = a;
}

// ===================== dense kernels =====================
// NOTE: macro parameter must NOT be named `w` (preprocessor token capture on .w)
#define FMA4(ar, xs, wv)            \
  ar[0] = fmaf(xs, wv.x, ar[0]);    \
  ar[1] = fmaf(xs, wv.y, ar[1]);    \
  ar[2] = fmaf(xs, wv.z, ar[2]);    \
  ar[3] = fmaf(xs, wv.w, ar[3]);

// hs[n][j] = dinv[n] * (x[n] @ W1)[j]  (+ acc init for fallback path)
// Two-phase W staging: 32 KiB LDS -> 5 blocks/CU (was 64 KiB -> 2 blocks/CU,
// OccupancyPercent 18, VALUBusy 26 -> latency-bound).
__global__ __launch_bounds__(256) void k_gemm1(const float* __restrict__ x,
                                               const float* __restrict__ W1,
                                               const float* __restrict__ dinv,
                                               float* __restrict__ hs,
                                               float* __restrict__ acc, int N,
                                               int write_acc) {
  __shared__ float Wl[128 * HD];  // 32 KiB half-tile of W1
  int tid = threadIdx.x;
  int tn = tid >> 4, tj = tid & 15;
  int n0 = blockIdx.x * 64 + tn * 4;
  int j0 = tj * 4;

  const float* xp0 = x + (size_t)(n0 + 0 < N ? n0 + 0 : N - 1) * CIN;
  const float* xp1 = x + (size_t)(n0 + 1 < N ? n0 + 1 : N - 1) * CIN;
  const float* xp2 = x + (size_t)(n0 + 2 < N ? n0 + 2 : N - 1) * CIN;
  const float* xp3 = x + (size_t)(n0 + 3 < N ? n0 + 3 : N - 1) * CIN;

  float a[4][4] = {};
#pragma unroll
  for (int kh = 0; kh < 2; ++kh) {
#pragma unroll
    for (int i = 0; i < (128 * HD) / 256; ++i)
      Wl[tid + i * 256] = W1[kh * 128 * HD + tid + i * 256];
    __syncthreads();
    int cbase = kh * 128;
    for (int c = 0; c < 128; c += 4) {
      float4 w0 = *(const float4*)&Wl[(c + 0) * HD + j0];
      float4 w1 = *(const float4*)&Wl[(c + 1) * HD + j0];
      float4 w2 = *(const float4*)&Wl[(c + 2) * HD + j0];
      float4 w3 = *(const float4*)&Wl[(c + 3) * HD + j0];
      float4 x0 = *(const float4*)(xp0 + cbase + c);
      float4 x1 = *(const float4*)(xp1 + cbase + c);
      float4 x2 = *(const float4*)(xp2 + cbase + c);
      float4 x3 = *(const float4*)(xp3 + cbase + c);
      FMA4(a[0], x0.x, w0); FMA4(a[0], x0.y, w1); FMA4(a[0], x0.z, w2); FMA4(a[0], x0.w, w3);
      FMA4(a[1], x1.x, w0); FMA4(a[1], x1.y, w1); FMA4(a[1], x1.z, w2); FMA4(a[1], x1.w, w3);
      FMA4(a[2], x2.x, w0); FMA4(a[2], x2.y, w1); FMA4(a[2], x2.z, w2); FMA4(a[2], x2.w, w3);
      FMA4(a[3], x3.x, w0); FMA4(a[3], x3.y, w1); FMA4(a[3], x3.z, w2); FMA4(a[3], x3.w, w3);
    }
    __syncthreads();
  }

#pragma unroll
  for (int i = 0; i < 4; ++i) {
    int n = n0 + i;
    if (n < N) {
      float dv = dinv[n];
      float4 v = make_float4(a[i][0] * dv, a[i][1] * dv, a[i][2] * dv, a[i][3] * dv);
      *(float4*)&hs[(size_t)n * HD + j0] = v;
      if (write_acc) *(float4*)&acc[(size_t)n * HD + j0] = v;
    }
  }
}

// fallback scatter-add path (atomics) — used only if ws_size too small for CSR
__global__ __launch_bounds__(256) void k_scatter(const int* __restrict__ src,
                                                 const int* __restrict__ dst,
                                                 const float* __restrict__ hs,
                                                 float* __restrict__ acc, int E) {
  int t = blockIdx.x * 256 + threadIdx.x;
  int e = t >> 4;
  if (e < E) {
    int q = (t & 15) * 4;
    int s = src[e], d = dst[e];
    float4 v = *(const float4*)&hs[(size_t)s * HD + q];
    float* p = &acc[(size_t)d * HD + q];
    atomicAdd(p + 0, v.x);
    atomicAdd(p + 1, v.y);
    atomicAdd(p + 2, v.z);
    atomicAdd(p + 3, v.w);
  }
}

__global__ __launch_bounds__(256) void k_deg(const int* __restrict__ dst,
                                             float* __restrict__ deg, int E) {
  int e = blockIdx.x * 256 + threadIdx.x;
  if (e < E) atomicAdd(&deg[dst[e]], 1.0f);
}
__global__ __launch_bounds__(256) void k_dinv(float* __restrict__ deg, int N) {
  int i = blockIdx.x * 256 + threadIdx.x;
  if (i < N) deg[i] = rsqrtf(deg[i] + 1.0f);
}

// h1 = relu(acc*dinv + b1); hs = h1*dinv; acc = same (fallback path only)
__global__ __launch_bounds__(256) void k_fin1(const float* __restrict__ b1,
                                              const float* __restrict__ dinv,
                                              float* __restrict__ acc,
                                              float* __restrict__ hs, int N64) {
  int t = blockIdx.x * 256 + threadIdx.x;
  if (t < N64) {
    int n = t >> 6, j = t & 63;
    float dv = dinv[n];
    float v = fmaf(acc[t], dv, b1[j]);
    v = fmaxf(v, 0.0f);
    v *= dv;
    hs[t] = v;
    acc[t] = v;
  }
}

__device__ inline float fast_tanh(float v) {
  v = fminf(fmaxf(v, -15.0f), 15.0f);
  float e2 = __expf(2.0f * v);
  return (e2 - 1.0f) * __builtin_amdgcn_rcpf(e2 + 1.0f);
}

// out[n][c] = tanh(dinv[n]*acc2[n][:] @ W2[:, c] + b2[c])
__global__ __launch_bounds__(256) void k_gemm2(const float* __restrict__ acc2,
                                               const float* __restrict__ W2,
                                               const float* __restrict__ dinv,
                                               const float* __restrict__ b2,
                                               float* __restrict__ out, int N) {
  __shared__ float Wl[HD * 64];  // [k][jj] chunk of 64 cols, 16 KiB
  int tid = threadIdx.x;
  int cb = blockIdx.y * 64;
#pragma unroll
  for (int i = 0; i < (HD * 64) / 256; ++i) {
    int idx = tid + i * 256;
    Wl[idx] = W2[(idx >> 6) * 256 + cb + (idx & 63)];
  }
  __syncthreads();

  int tn = tid >> 4, tj = tid & 15;
  int n0 = blockIdx.x * 64 + tn * 4;
  int j0 = tj * 4;

  const float* hp0 = acc2 + (size_t)(n0 + 0 < N ? n0 + 0 : N - 1) * HD;
  const float* hp1 = acc2 + (size_t)(n0 + 1 < N ? n0 + 1 : N - 1) * HD;
  const float* hp2 = acc2 + (size_t)(n0 + 2 < N ? n0 + 2 : N - 1) * HD;
  const float* hp3 = acc2 + (size_t)(n0 + 3 < N ? n0 + 3 : N - 1) * HD;

  float a[4][4] = {};
  for (int k = 0; k < HD; k += 4) {
    float4 w0 = *(const float4*)&Wl[(k + 0) * 64 + j0];
    float4 w1 = *(const float4*)&Wl[(k + 1) * 64 + j0];
    float4 w2 = *(const float4*)&Wl[(k + 2) * 64 + j0];
    float4 w3 = *(const float4*)&Wl[(k + 3) * 64 + j0];
    float4 x0 = *(const float4*)(hp0 + k);
    float4 x1 = *(const float4*)(hp1 + k);
    float4 x2 = *(const float4*)(hp2 + k);
    float4 x3 = *(const float4*)(hp3 + k);
    FMA4(a[0], x0.x, w0); FMA4(a[0], x0.y, w1); FMA4(a[0], x0.z, w2); FMA4(a[0], x0.w, w3);
    FMA4(a[1], x1.x, w0); FMA4(a[1], x1.y, w1); FMA4(a[1], x1.z, w2); FMA4(a[1], x1.w, w3);
    FMA4(a[2], x2.x, w0); FMA4(a[2], x2.y, w1); FMA4(a[2], x2.z, w2); FMA4(a[2], x2.w, w3);
    FMA4(a[3], x3.x, w0); FMA4(a[3], x3.y, w1); FMA4(a[3], x3.z, w2); FMA4(a[3], x3.w, w3);
  }

#pragma unroll
  for (int i = 0; i < 4; ++i) {
    int n = n0 + i;
    if (n < N) {
      float dv = dinv[n];
      float4 r;
      r.x = fast_tanh(fmaf(a[i][0], dv, b2[cb + j0 + 0]));
      r.y = fast_tanh(fmaf(a[i][1], dv, b2[cb + j0 + 1]));
      r.z = fast_tanh(fmaf(a[i][2], dv, b2[cb + j0 + 2]));
      r.w = fast_tanh(fmaf(a[i][3], dv, b2[cb + j0 + 3]));
      *(float4*)&out[(size_t)n * 256 + cb + j0] = r;
    }
  }
}

extern "C" void kernel_launch(void* const* d_in, const int* in_sizes, int n_in,
                              void* d_out, int out_size, void* d_ws, size_t ws_size,
                              hipStream_t stream) {
  const float* x  = (const float*)d_in[0];
  const int*   ei = (const int*)d_in[1];
  const float* W1 = (const float*)d_in[2];
  const float* b1 = (const float*)d_in[3];
  const float* W2 = (const float*)d_in[4];
  const float* b2 = (const float*)d_in[5];
  float* out = (float*)d_out;

  int N = in_sizes[0] / CIN;   // 100000
  int E = in_sizes[1] / 2;     // 1600000
  const int* src = ei;
  const int* dst = ei + E;

  auto align256 = [](size_t v) { return (v + 255) & ~(size_t)255; };
  size_t nb = align256((size_t)N * 4);
  size_t eb = align256((size_t)E * 4);
  size_t fb = align256((size_t)N * HD * 4);

  // CSR layout: dinv | deg | rowstart | fill | partials | csr | bufA | bufB
  size_t need = nb * 4 + align256(512 * 4) + eb + fb * 2;

  char* ws = (char*)d_ws;
  int nblk = (N + 255) / 256;

  if (ws_size >= need) {
    float* dinv     = (float*)ws;
    int*   deg      = (int*)(ws + nb);
    int*   rowstart = (int*)(ws + nb * 2);
    int*   fillc    = (int*)(ws + nb * 3);
    int*   partials = (int*)(ws + nb * 4);
    int*   csr      = (int*)(ws + nb * 4 + align256(512 * 4));
    float* bufA     = (float*)(ws + nb * 4 + align256(512 * 4) + eb);
    float* bufB     = bufA + (size_t)N * HD;

    hipMemsetAsync(deg,   0, (size_t)N * 4, stream);
    hipMemsetAsync(fillc, 0, (size_t)N * 4, stream);
    k_hist <<<(E + 255) / 256, 256, 0, stream>>>(dst, deg, E);
    k_dinv2<<<nblk, 256, 0, stream>>>(deg, dinv, N);
    k_scan1<<<nblk, 256, 0, stream>>>(deg, rowstart, partials, N);
    k_scan2<<<1, 512, 0, stream>>>(partials, nblk);
    k_scan3<<<nblk, 256, 0, stream>>>(rowstart, partials, N);
    k_fill <<<(E + 255) / 256, 256, 0, stream>>>(src, dst, rowstart, fillc, csr, E);

    size_t aggGrid = ((size_t)N * 16 + 255) / 256;
    // gemm1: x -> bufA (hs1); acc write disabled (agg reads hs[n] for self-loop)
    k_gemm1<<<(N + 63) / 64, 256, 0, stream>>>(x, W1, dinv, bufA, bufB, N, 0);
    // agg1 fused with layer-1 finalize: bufA -> bufB (= dinv-scaled h1 messages)
    k_agg<true> <<<aggGrid, 256, 0, stream>>>(rowstart, deg, csr, bufA, bufB, dinv, b1, N);
    // agg2 plain: bufB -> bufA
    k_agg<false><<<aggGrid, 256, 0, stream>>>(rowstart, deg, csr, bufB, bufA, dinv, b1, N);
    dim3 g2((N + 63) / 64, 4);
    k_gemm2<<<g2, 256, 0, stream>>>(bufA, W2, dinv, b2, out, N);
  } else {
    // fallback: atomic scatter path (verified working)
    float* dinv = (float*)ws;
    float* bufA = (float*)(ws + nb);
    float* bufB = bufA + (size_t)N * HD;

    hipMemsetAsync(dinv, 0, (size_t)N * 4, stream);
    k_deg <<<(E + 255) / 256, 256, 0, stream>>>(dst, dinv, E);
    k_dinv<<<nblk, 256, 0, stream>>>(dinv, N);
    k_gemm1<<<(N + 63) / 64, 256, 0, stream>>>(x, W1, dinv, bufA, bufB, N, 1);
    k_scatter<<<((size_t)E * 16 + 255) / 256, 256, 0, stream>>>(src, dst, bufA, bufB, E);
    k_fin1<<<((size_t)N * HD + 255) / 256, 256, 0, stream>>>(b1, dinv, bufB, bufA, N * HD);
    k_scatter<<<((size_t)E * 16 + 255) / 256, 256, 0, stream>>>(src, dst, bufA, bufB, E);
    dim3 g2((N + 63) / 64, 4);
    k_gemm2<<<g2, 256, 0, stream>>>(bufB, W2, dinv, b2, out, N);
  }
}